// Round 6
// baseline (95.985 us; speedup 1.0000x reference)
//
#include <hip/hip_runtime.h>
#include <math.h>

#define HD 512
#define WD 512
#define NP 255          // patch grid = 255 x 255
#define LK 7225         // patches per kk group (65025/9)
#define BATCH 32
#define RB 64           // r's per chunk
#define NCH 113         // ceil(LK/RB)
#define QB 8            // blocks per (b,di)
#define G  15           // chunks per block (QB*G = 120 >= 113)
#define NTHR 192        // 3 waves; dj = tid%3, idx = tid/3
#define ROWS 4          // max pi2 span for 576 consecutive ll
#define BUFF (3 * ROWS * WD)   // 6144 floats per LDS buffer (24.6 KB)

// Semantics (reference's flat reshape (b,9,L)->(b,L,9)):
//   l = kk*7225 + r ; (di,dj) = (kk/3, kk%3) fixed within a 9-group
//   k in 0..8: ll = 9r+k -> pixel (2*(ll/255)+di, 2*(ll%255)+dj)
//   argmin/argmax |a-c| (first-occurrence), s = c[argmin]+c[argmax]
//   broadcast to 2x2 (3x3 at edges) block of patch (l/255, l%255); row/col 511 = 0.
//
// Structure (T3+T4): global_load_lds direct staging (no VGPR round-trip),
// double-buffered LDS, counted s_waitcnt vmcnt(8) + raw s_barrier so chunk
// c+1's loads stay in flight across the barrier while chunk c computes.
// Bank conflicts on compute reads avoided by mixing dj in-wave (dj=tid%3):
// lane cols = 18*(i/3) + i%3 -> both parities -> ~2-way (free).

typedef const __attribute__((address_space(1))) void* gp1_t;
typedef __attribute__((address_space(3))) void* lp3_t;

__global__ __launch_bounds__(NTHR) void dc_pool_kernel(
    const float* __restrict__ anchor,
    const float* __restrict__ pos,
    const float* __restrict__ neg,
    float* __restrict__ out0,
    float* __restrict__ out1)
{
    __shared__ float lds[2][BUFF];

    int bid = blockIdx.x;
    int q   = bid % QB;
    int t2  = bid / QB;
    int di  = t2 % 3;
    int b   = t2 / 3;

    const size_t plane = (size_t)HD * WD;
    const float* A = anchor + (size_t)b * plane;
    const float* P = pos    + (size_t)b * plane;
    const float* N = neg    + (size_t)b * plane;
    float* O0 = out0 + (size_t)b * plane;
    float* O1 = out1 + (size_t)b * plane;

    int tid   = threadIdx.x;
    int dj    = tid % 3;           // mixed within wave -> conflict-free LDS reads
    int idx   = tid / 3;           // 0..63
    int wbase = tid & ~63;         // wave-uniform lane-group base

    // ---- stage chunk rb's 4 rows x 512 x 3 tensors into lds[bsel] ----
    // 1536 16B-chunks = 8 rounds x 192 lanes; chunk u -> floats [4u,4u+4) ->
    // tensor u/512, row (u%512)/128, col4 u%128. LDS dest is linear in u
    // (global_load_lds: wave-uniform base + lane*16).
    auto stage = [&](int c, int bsel) {
        int rb = c * QB + q;
        if (rb > NCH - 1) rb = NCH - 1;          // padding slots re-stage last chunk
        int pi2min = (9 * (rb * RB)) / NP;
        #pragma unroll
        for (int J = 0; J < 8; ++J) {
            int u      = J * NTHR + tid;
            int tensor = u >> 9;                 // /512
            int rem    = u & 511;
            int row    = rem >> 7;               // /128
            int col4   = rem & 127;
            int prow   = pi2min + row;
            if (prow > 254) prow = 254;          // clamp padding rows in-bounds
            const float* g = (tensor == 0 ? A : (tensor == 1 ? P : N))
                             + (2 * prow + di) * WD + col4 * 4;
            float* l = &lds[bsel][(size_t)(J * NTHR + wbase) * 4];
            __builtin_amdgcn_global_load_lds((gp1_t)(const void*)g,
                                             (lp3_t)(void*)l, 16, 0, 0);
        }
    };

    // ---- compute chunk rb from lds[bsel] ----
    auto compute = [&](int c, int bsel) {
        int rb     = c * QB + q;
        int r0     = rb * RB;
        int rcount = min(RB, LK - r0);           // <=0 for padding slots
        if (idx < rcount) {
            int pi2min = (9 * r0) / NP;
            int r    = r0 + idx;
            int ll0  = 9 * r;
            int pi2  = ll0 / NP;
            int pj2  = ll0 - pi2 * NP;
            const float* sA = &lds[bsel][0];
            const float* sP = &lds[bsel][ROWS * WD];
            const float* sN = &lds[bsel][2 * ROWS * WD];
            int base  = (pi2 - pi2min) * WD + 2 * pj2 + dj;
            int wrapk = NP - pj2;                // k >= wrapk -> next row (+512-510 = +2)

            float minvP = 0.f, maxvP = 0.f, mindP = INFINITY, maxdP = -INFINITY;
            float minvN = 0.f, maxvN = 0.f, mindN = INFINITY, maxdN = -INFINITY;
            #pragma unroll
            for (int k = 0; k < 9; ++k) {
                int lo = base + 2 * k + ((k >= wrapk) ? 2 : 0);
                float a = sA[lo];
                float p = sP[lo];
                float n = sN[lo];
                float dp = fabsf(a - p);
                float dn = fabsf(a - n);
                if (dp < mindP) { mindP = dp; minvP = p; }   // first-occurrence argmin
                if (dp > maxdP) { maxdP = dp; maxvP = p; }   // first-occurrence argmax
                if (dn < mindN) { mindN = dn; minvN = n; }
                if (dn > maxdN) { maxdN = dn; maxvN = n; }
            }
            float s0 = minvP + maxvP;
            float s1 = minvN + maxvN;

            int kk  = 3 * di + dj;
            int l   = kk * LK + r;
            int piy = l / NP;
            int pjx = l - piy * NP;
            int y0  = 2 * piy;
            int x0  = 2 * pjx;
            bool right  = (pjx == NP - 1);
            bool bottom = (piy == NP - 1);
            int ny = bottom ? 3 : 2;

            for (int yy = 0; yy < ny; ++yy) {
                float* p0 = O0 + (size_t)(y0 + yy) * WD + x0;
                float* p1 = O1 + (size_t)(y0 + yy) * WD + x0;
                if (right) {    // cols 508,509,510 = s ; col 511 = 0
                    *reinterpret_cast<float4*>(p0) = make_float4(s0, s0, s0, 0.f);
                    *reinterpret_cast<float4*>(p1) = make_float4(s1, s1, s1, 0.f);
                } else {
                    *reinterpret_cast<float2*>(p0) = make_float2(s0, s0);
                    *reinterpret_cast<float2*>(p1) = make_float2(s1, s1);
                }
            }
            if (bottom) {       // row 511 = 0
                float* p0 = O0 + (size_t)(HD - 1) * WD + x0;
                float* p1 = O1 + (size_t)(HD - 1) * WD + x0;
                if (right) {
                    *reinterpret_cast<float4*>(p0) = make_float4(0.f, 0.f, 0.f, 0.f);
                    *reinterpret_cast<float4*>(p1) = make_float4(0.f, 0.f, 0.f, 0.f);
                } else {
                    *reinterpret_cast<float2*>(p0) = make_float2(0.f, 0.f);
                    *reinterpret_cast<float2*>(p1) = make_float2(0.f, 0.f);
                }
            }
        }
    };

    // ---- pipelined loop: STAGE(c+1) in flight across barrier during compute(c) ----
    stage(0, 0);
    #pragma unroll 1
    for (int c = 0; c < G; ++c) {
        int  bsel = c & 1;
        bool pf   = (c + 1 < G);
        if (pf) stage(c + 1, bsel ^ 1);          // 8 more loads in flight
        if (pf) {
            // wait chunk-c's 8 loads (oldest); chunk-(c+1)'s 8 may remain outstanding.
            asm volatile("s_waitcnt vmcnt(8)" ::: "memory");
        } else {
            asm volatile("s_waitcnt vmcnt(0)" ::: "memory");
        }
        __builtin_amdgcn_s_barrier();            // all waves' chunk-c data landed
        compute(c, bsel);
        if (pf) __builtin_amdgcn_s_barrier();    // reads done before stage(c+2) overwrites
    }
}

extern "C" void kernel_launch(void* const* d_in, const int* in_sizes, int n_in,
                              void* d_out, int out_size, void* d_ws, size_t ws_size,
                              hipStream_t stream) {
    const float* anchor = (const float*)d_in[0];
    const float* pos    = (const float*)d_in[1];
    const float* neg    = (const float*)d_in[2];
    float* out0 = (float*)d_out;
    float* out1 = out0 + (size_t)BATCH * HD * WD;

    int grid = BATCH * 3 * QB;   // 32 * 3 * 8 = 768 blocks = 3 per CU exactly
    dc_pool_kernel<<<grid, NTHR, 0, stream>>>(anchor, pos, neg, out0, out1);
}

// Round 7
// 47.172 us; speedup vs baseline: 2.0348x; 2.0348x over previous
//
#include <hip/hip_runtime.h>
#include <math.h>

#define HD 512
#define WD 512
#define NP 255          // patch grid = 255 x 255
#define LK 7225         // patches per kk group (65025/9); 7225 = 85*85
#define BATCH 32
#define RB 85           // r's per chunk -> NCH = 85 chunks exactly, no padding
#define NCH 85
#define NTHR 256        // 4 waves; 255 compute lanes (dj=tid%3, idx=tid/3)
#define ROWS 4          // 765 consecutive ll span <= 4 image rows
#define TEN (ROWS * WD) // 2048 floats per tensor in LDS

// Semantics (reference's flat reshape (b,9,L)->(b,L,9)):
//   l = kk*7225 + r ; (di,dj) = (kk/3, kk%3) fixed within a 9-group
//   k in 0..8: ll = 9r+k -> pixel (2*(ll/255)+di, 2*(ll%255)+dj)
//   argmin/argmax |a-c| (first-occurrence), s = c[argmin]+c[argmax]
//   broadcast to 2x2 (3x3 at edges) block of patch (l/255, l%255); row/col 511 = 0.
//
// One-shot blocks, max TLP (R5 lesson: this op wants streams, not schedule
// depth): 24.6 KB LDS -> 6 blocks/CU -> 6 concurrent staging streams + 24
// waves per CU. Staging via global_load_lds width-16 (not sink-able by the
// compiler, no VGPR round-trip). dj mixed in-wave so LDS compute reads are
// <=3-way bank aliased (~free); one vmcnt drain per block.

typedef const __attribute__((address_space(1))) void* gp1_t;
typedef __attribute__((address_space(3))) void* lp3_t;

__global__ __launch_bounds__(NTHR) void dc_pool_kernel(
    const float* __restrict__ anchor,
    const float* __restrict__ pos,
    const float* __restrict__ neg,
    float* __restrict__ out0,
    float* __restrict__ out1)
{
    __shared__ float lds[3 * TEN];   // 24576 B: A | P | N, each 4 rows x 512

    int bid   = blockIdx.x;
    int chunk = bid % NCH;
    int t2    = bid / NCH;
    int di    = t2 % 3;
    int b     = t2 / 3;

    const size_t plane = (size_t)HD * WD;
    const float* A = anchor + (size_t)b * plane;
    const float* P = pos    + (size_t)b * plane;
    const float* N = neg    + (size_t)b * plane;
    float* O0 = out0 + (size_t)b * plane;
    float* O1 = out1 + (size_t)b * plane;

    int tid    = threadIdx.x;
    int r0     = chunk * RB;
    int llb    = 9 * r0;
    int pi2min = llb / NP;

    // ---- stage 4 rows x 512 x 3 tensors: 1536 x 16B = 6 rounds x 256 lanes ----
    // u = J*256+tid -> float4 u of layout [tensor][row][col]; LDS dst linear in u
    // (wave-uniform base + lane*16, per global_load_lds semantics).
    {
        int wbase = tid & ~63;
        #pragma unroll
        for (int J = 0; J < 6; ++J) {
            int u      = J * NTHR + tid;
            int tensor = u >> 9;                 // /512
            int rem    = u & 511;
            int row    = rem >> 7;               // /128
            int col4   = rem & 127;
            int prow   = pi2min + row;
            if (prow > NP - 1) prow = NP - 1;    // clamp (re-stages row 254; unused)
            const float* g = (tensor == 0 ? A : (tensor == 1 ? P : N))
                             + (2 * prow + di) * WD + col4 * 4;
            float* l = &lds[(size_t)(J * NTHR + wbase) * 4];
            __builtin_amdgcn_global_load_lds((gp1_t)(const void*)g,
                                             (lp3_t)(void*)l, 16, 0, 0);
        }
    }
    __syncthreads();   // drains vmcnt(0); one-shot, so this is the only stall

    if (tid >= 3 * RB) return;   // 255 compute lanes

    int dj  = tid % 3;           // mixed in-wave -> <=3-way LDS bank aliasing
    int idx = tid / 3;           // 0..84

    int r    = r0 + idx;
    int ll0  = 9 * r;
    int pi2  = ll0 / NP;
    int pj2  = ll0 - pi2 * NP;
    int base = (pi2 - pi2min) * WD + 2 * pj2 + dj;
    int wrapk = NP - pj2;        // k >= wrapk -> next image row (+2: 512-510)

    float minvP = 0.f, maxvP = 0.f, mindP = INFINITY, maxdP = -INFINITY;
    float minvN = 0.f, maxvN = 0.f, mindN = INFINITY, maxdN = -INFINITY;
    #pragma unroll
    for (int k = 0; k < 9; ++k) {
        int lo = base + 2 * k + ((k >= wrapk) ? 2 : 0);
        float a = lds[lo];
        float p = lds[TEN + lo];
        float n = lds[2 * TEN + lo];
        float dp = fabsf(a - p);
        float dn = fabsf(a - n);
        if (dp < mindP) { mindP = dp; minvP = p; }   // first-occurrence argmin
        if (dp > maxdP) { maxdP = dp; maxvP = p; }   // first-occurrence argmax
        if (dn < mindN) { mindN = dn; minvN = n; }
        if (dn > maxdN) { maxdN = dn; maxvN = n; }
    }
    float s0 = minvP + maxvP;
    float s1 = minvN + maxvN;

    // ---- scatter to output ----
    int kk  = 3 * di + dj;
    int l   = kk * LK + r;
    int piy = l / NP;
    int pjx = l - piy * NP;
    int y0  = 2 * piy;
    int x0  = 2 * pjx;
    bool right  = (pjx == NP - 1);
    bool bottom = (piy == NP - 1);
    int ny = bottom ? 3 : 2;

    for (int yy = 0; yy < ny; ++yy) {
        float* p0 = O0 + (size_t)(y0 + yy) * WD + x0;
        float* p1 = O1 + (size_t)(y0 + yy) * WD + x0;
        if (right) {    // cols 508,509,510 = s ; col 511 = 0
            *reinterpret_cast<float4*>(p0) = make_float4(s0, s0, s0, 0.f);
            *reinterpret_cast<float4*>(p1) = make_float4(s1, s1, s1, 0.f);
        } else {
            *reinterpret_cast<float2*>(p0) = make_float2(s0, s0);
            *reinterpret_cast<float2*>(p1) = make_float2(s1, s1);
        }
    }
    if (bottom) {       // row 511 = 0
        float* p0 = O0 + (size_t)(HD - 1) * WD + x0;
        float* p1 = O1 + (size_t)(HD - 1) * WD + x0;
        if (right) {
            *reinterpret_cast<float4*>(p0) = make_float4(0.f, 0.f, 0.f, 0.f);
            *reinterpret_cast<float4*>(p1) = make_float4(0.f, 0.f, 0.f, 0.f);
        } else {
            *reinterpret_cast<float2*>(p0) = make_float2(0.f, 0.f);
            *reinterpret_cast<float2*>(p1) = make_float2(0.f, 0.f);
        }
    }
}

extern "C" void kernel_launch(void* const* d_in, const int* in_sizes, int n_in,
                              void* d_out, int out_size, void* d_ws, size_t ws_size,
                              hipStream_t stream) {
    const float* anchor = (const float*)d_in[0];
    const float* pos    = (const float*)d_in[1];
    const float* neg    = (const float*)d_in[2];
    float* out0 = (float*)d_out;
    float* out1 = out0 + (size_t)BATCH * HD * WD;

    int grid = BATCH * 3 * NCH;   // 32 * 3 * 85 = 8160 blocks
    dc_pool_kernel<<<grid, NTHR, 0, stream>>>(anchor, pos, neg, out0, out1);
}

// Round 8
// 40.282 us; speedup vs baseline: 2.3829x; 1.1711x over previous
//
#include <hip/hip_runtime.h>
#include <math.h>

#define HD 512
#define WD 512
#define NP 255            // patch grid = 255 x 255
#define LK 7225           // patches per kk group (65025/9); 7225 = 85*85
#define BATCH 32
#define RB 85             // r's per chunk
#define CH 85             // chunks; RB*9 = 765 = 3*255 -> chunk spans EXACTLY 3 pi2-rows
#define NTHR 256          // 4 waves; 255 compute lanes (dj=tid%3, m=tid/3)
#define IMR 7             // contiguous image rows staged: [6c, 6c+6]
#define TENF (IMR * WD)   // 3584 floats per tensor
#define NF4 (3 * TENF / 4) // 2688 float4 stage chunks

// Semantics (reference's flat reshape (b,9,L)->(b,L,9)):
//   l = kk*7225 + r ; (di,dj) = (kk/3, kk%3) fixed within a 9-group
//   k in 0..8: ll = 9r+k -> pixel (2*(ll/255)+di, 2*(ll%255)+dj)
//   argmin/argmax |a-c| (first-occurrence), s = c[argmin]+c[argmax]
//   broadcast to 2x2 (3x3 at edges) block of patch (l/255, l%255); row/col 511 = 0.
//
// R7: fuse all 3 di per block. Chunk c needs pi2 rows {3c..3c+2}; over di the
// image rows [6c, 6c+6] are CONTIGUOUS -> fully sequential HBM reads, no
// even-row double-fetch (R2..R6 read every-other-row per (b,di) family and
// plateaued at ~3.3 TB/s across four structures). 42KB LDS, 3 blocks/CU.

typedef const __attribute__((address_space(1))) void* gp1_t;
typedef __attribute__((address_space(3))) void* lp3_t;

__global__ __launch_bounds__(NTHR) void dc_pool_kernel(
    const float* __restrict__ anchor,
    const float* __restrict__ pos,
    const float* __restrict__ neg,
    float* __restrict__ out0,
    float* __restrict__ out1)
{
    __shared__ float lds[3 * TENF];   // A | P | N, each 7 rows x 512 (43008 B)

    int bid   = blockIdx.x;
    int chunk = bid % CH;
    int b     = bid / CH;

    const size_t plane = (size_t)HD * WD;
    const float* A = anchor + (size_t)b * plane;
    const float* P = pos    + (size_t)b * plane;
    const float* N = neg    + (size_t)b * plane;
    float* O0 = out0 + (size_t)b * plane;
    float* O1 = out1 + (size_t)b * plane;

    int tid   = threadIdx.x;
    int wbase = tid & ~63;
    int row0  = 6 * chunk;            // first staged image row (6*84+6 = 510 <= 511)

    // ---- stage 7 contiguous rows x 512 x 3 tensors: 2688 x 16B, 10.5 rounds ----
    // u -> tensor u/896, row (u%896)/128, col4 u%128 ; LDS dst linear in u
    // (wave-uniform base + lane*16 per global_load_lds semantics).
    #pragma unroll
    for (int J = 0; J < 11; ++J) {
        int u = J * NTHR + tid;
        if (u < NF4) {                // wave-uniform: J<10 all, J=10 waves 0-1 only
            int tensor = u / 896;
            int rem    = u - tensor * 896;
            int rr     = rem >> 7;
            int col4   = rem & 127;
            const float* g = (tensor == 0 ? A : (tensor == 1 ? P : N))
                             + (row0 + rr) * WD + col4 * 4;
            float* l = &lds[(size_t)(J * NTHR + wbase) * 4];
            __builtin_amdgcn_global_load_lds((gp1_t)(const void*)g,
                                             (lp3_t)(void*)l, 16, 0, 0);
        }
    }
    __syncthreads();   // implicit vmcnt(0) drain; one-shot block

    if (tid >= 3 * RB) return;        // 255 compute lanes

    int dj = tid % 3;                 // mixed in-wave -> bank aliasing ~2-3-way (free-ish)
    int m  = tid / 3;                 // 0..84
    int r  = chunk * RB + m;

    int loc   = 9 * m;                // ll - 765*chunk, 0..756
    int rrb   = loc / NP;             // 0..2 (pi2 - 3*chunk)
    int pj2   = loc - rrb * NP;
    int base0 = rrb * 1024 + 2 * pj2 + dj;  // row 2*rrb (di=0), col 2*pj2+dj
    int wrapk = NP - pj2;             // k >= wrapk -> +2 image rows, col-510: +514
                                      // (m=84 has wrapk=9 -> no wrap; rows stay <= 6)

    #pragma unroll
    for (int di = 0; di < 3; ++di) {
        float minvP = 0.f, maxvP = 0.f, mindP = INFINITY, maxdP = -INFINITY;
        float minvN = 0.f, maxvN = 0.f, mindN = INFINITY, maxdN = -INFINITY;
        #pragma unroll
        for (int k = 0; k < 9; ++k) {
            int lo = base0 + 512 * di + 2 * k + ((k >= wrapk) ? 514 : 0);
            float a = lds[lo];
            float p = lds[TENF + lo];
            float n = lds[2 * TENF + lo];
            float dp = fabsf(a - p);
            float dn = fabsf(a - n);
            if (dp < mindP) { mindP = dp; minvP = p; }   // first-occurrence argmin
            if (dp > maxdP) { maxdP = dp; maxvP = p; }   // first-occurrence argmax
            if (dn < mindN) { mindN = dn; minvN = n; }
            if (dn > maxdN) { maxdN = dn; maxvN = n; }
        }
        float s0 = minvP + maxvP;
        float s1 = minvN + maxvN;

        // ---- scatter to output ----
        int kk  = 3 * di + dj;
        int l   = kk * LK + r;
        int piy = l / NP;
        int pjx = l - piy * NP;
        int y0  = 2 * piy;
        int x0  = 2 * pjx;
        bool right  = (pjx == NP - 1);
        bool bottom = (piy == NP - 1);
        int ny = bottom ? 3 : 2;

        for (int yy = 0; yy < ny; ++yy) {
            float* p0 = O0 + (size_t)(y0 + yy) * WD + x0;
            float* p1 = O1 + (size_t)(y0 + yy) * WD + x0;
            if (right) {    // cols 508,509,510 = s ; col 511 = 0
                *reinterpret_cast<float4*>(p0) = make_float4(s0, s0, s0, 0.f);
                *reinterpret_cast<float4*>(p1) = make_float4(s1, s1, s1, 0.f);
            } else {
                *reinterpret_cast<float2*>(p0) = make_float2(s0, s0);
                *reinterpret_cast<float2*>(p1) = make_float2(s1, s1);
            }
        }
        if (bottom) {       // row 511 = 0
            float* p0 = O0 + (size_t)(HD - 1) * WD + x0;
            float* p1 = O1 + (size_t)(HD - 1) * WD + x0;
            if (right) {
                *reinterpret_cast<float4*>(p0) = make_float4(0.f, 0.f, 0.f, 0.f);
                *reinterpret_cast<float4*>(p1) = make_float4(0.f, 0.f, 0.f, 0.f);
            } else {
                *reinterpret_cast<float2*>(p0) = make_float2(0.f, 0.f);
                *reinterpret_cast<float2*>(p1) = make_float2(0.f, 0.f);
            }
        }
    }
}

extern "C" void kernel_launch(void* const* d_in, const int* in_sizes, int n_in,
                              void* d_out, int out_size, void* d_ws, size_t ws_size,
                              hipStream_t stream) {
    const float* anchor = (const float*)d_in[0];
    const float* pos    = (const float*)d_in[1];
    const float* neg    = (const float*)d_in[2];
    float* out0 = (float*)d_out;
    float* out1 = out0 + (size_t)BATCH * HD * WD;

    int grid = BATCH * CH;   // 32 * 85 = 2720 blocks
    dc_pool_kernel<<<grid, NTHR, 0, stream>>>(anchor, pos, neg, out0, out1);
}

// Round 9
// 38.472 us; speedup vs baseline: 2.4949x; 1.0470x over previous
//
#include <hip/hip_runtime.h>
#include <math.h>

#define HD 512
#define WD 512
#define NP 255            // patch grid = 255 x 255
#define LK 7225           // patches per kk group; 7225 = 85*85
#define BATCH 32
#define RB 85             // r's per chunk (765 ll = exactly 3 pi2-rows)
#define CH 85
#define NTHR 256
#define IMR 7             // contiguous image rows staged: [6c, 6c+6]
#define TCOLS 288         // h=0: image cols [0,288) ; h=1: [240,512) + strip [0,16)
#define TENF (IMR * TCOLS)        // 2016 floats per tensor
#define NF4 (3 * TENF / 4)        // 1512 float4 stage ops
#define NWG (BATCH * CH * 2)      // 5440 blocks (divisible by 8 -> clean XCD swizzle)

// Semantics (reference's flat reshape (b,9,L)->(b,L,9)):
//   l = kk*7225 + r ; (di,dj) = (kk/3, kk%3) fixed within a 9-group
//   k in 0..8: ll = 9r+k -> pixel (2*(ll/255)+di, 2*(ll%255)+dj)
//   argmin/argmax |a-c| (first-occurrence), s = c[argmin]+c[argmax]
//   broadcast to 2x2 (3x3 at edges) block of patch (l/255, l%255); row/col 511 = 0.
//
// R8 = R7's contiguous-row fetch + R6's occupancy: split each chunk into two
// column-halves (24.2 KB LDS -> 6 blocks/CU -> 24 waves/CU). h=1 appends a
// 16-col strip of each row's left edge for the pj2>=247 groups that wrap to
// the next pi2-row (constant +578 index offset in the 288-col layout).
// XCD-swizzled bid so a chunk's halves/neighbors share an XCD L2.

typedef const __attribute__((address_space(1))) void* gp1_t;
typedef __attribute__((address_space(3))) void* lp3_t;

__global__ __launch_bounds__(NTHR) void dc_pool_kernel(
    const float* __restrict__ anchor,
    const float* __restrict__ pos,
    const float* __restrict__ neg,
    float* __restrict__ out0,
    float* __restrict__ out1)
{
    __shared__ float lds[3 * TENF];   // 24192 B -> 6 blocks/CU

    // XCD-aware swizzle (bijective: NWG % 8 == 0)
    int bid = blockIdx.x;
    int vid = (bid & 7) * (NWG / 8) + (bid >> 3);
    int c2    = vid % (CH * 2);
    int b     = vid / (CH * 2);
    int h     = c2 & 1;
    int chunk = c2 >> 1;

    const size_t plane = (size_t)HD * WD;
    const float* A = anchor + (size_t)b * plane;
    const float* P = pos    + (size_t)b * plane;
    const float* N = neg    + (size_t)b * plane;
    float* O0 = out0 + (size_t)b * plane;
    float* O1 = out1 + (size_t)b * plane;

    int tid   = threadIdx.x;
    int wbase = tid & ~63;
    int row0  = 6 * chunk;            // first staged image row (max 510)

    // ---- stage 7 rows x 288 cols x 3 tensors = 1512 x 16B, 6 rounds ----
    // u -> tensor u/504, row (u%504)/72, col4 (u%504)%72 ; LDS dst linear in u.
    // h=0: image col4 = c4 (cols [0,288)).
    // h=1: c4<68 -> cols [240,512) ; c4>=68 -> strip = same row's cols [0,16).
    #pragma unroll
    for (int J = 0; J < 6; ++J) {
        int u = J * NTHR + tid;
        if (u < NF4) {
            int tensor = u / 504;
            int rem    = u - tensor * 504;
            int rr     = rem / 72;
            int c4     = rem - rr * 72;
            int gc4    = (h == 0) ? c4 : (c4 < 68 ? 60 + c4 : c4 - 68);
            const float* g = (tensor == 0 ? A : (tensor == 1 ? P : N))
                             + (row0 + rr) * WD + gc4 * 4;
            float* l = &lds[(size_t)(J * NTHR + wbase) * 4];
            __builtin_amdgcn_global_load_lds((gp1_t)(const void*)g,
                                             (lp3_t)(void*)l, 16, 0, 0);
        }
    }
    __syncthreads();   // vmcnt drain; one-shot block, 6 blocks/CU hide it

    // ---- compute: h=0 handles groups with pj2<128 (43), h=1 the rest (42) ----
    int dj = tid % 3;
    int gi = tid / 3;
    int ng = 43 - h;
    if (gi >= ng) return;
    int m;
    if (h == 0) m = (gi < 15) ? gi      : ((gi < 29) ? gi + 14 : gi + 28);
    else        m = (gi < 14) ? gi + 15 : ((gi < 28) ? gi + 29 : gi + 43);

    int r    = chunk * RB + m;
    int loc  = 9 * m;                 // 0..756
    int rrb  = loc / NP;              // 0..2
    int pj2  = loc - rrb * NP;
    int base0 = 2 * rrb * TCOLS + 2 * pj2 + dj - (h ? 240 : 0);
    int wrapk = NP - pj2;             // <=8 only for h=1 (pj2>=247); strip offset +578

    #pragma unroll
    for (int di = 0; di < 3; ++di) {
        float minvP = 0.f, maxvP = 0.f, mindP = INFINITY, maxdP = -INFINITY;
        float minvN = 0.f, maxvN = 0.f, mindN = INFINITY, maxdN = -INFINITY;
        #pragma unroll
        for (int k = 0; k < 9; ++k) {
            int lo = base0 + di * TCOLS + 2 * k + ((k >= wrapk) ? 578 : 0);
            float a = lds[lo];
            float p = lds[TENF + lo];
            float n = lds[2 * TENF + lo];
            float dp = fabsf(a - p);
            float dn = fabsf(a - n);
            if (dp < mindP) { mindP = dp; minvP = p; }   // first-occurrence argmin
            if (dp > maxdP) { maxdP = dp; maxvP = p; }   // first-occurrence argmax
            if (dn < mindN) { mindN = dn; minvN = n; }
            if (dn > maxdN) { maxdN = dn; maxvN = n; }
        }
        float s0 = minvP + maxvP;
        float s1 = minvN + maxvN;

        // ---- scatter to output ----
        int kk  = 3 * di + dj;
        int l   = kk * LK + r;
        int piy = l / NP;
        int pjx = l - piy * NP;
        int y0  = 2 * piy;
        int x0  = 2 * pjx;
        bool right  = (pjx == NP - 1);
        bool bottom = (piy == NP - 1);
        int ny = bottom ? 3 : 2;

        for (int yy = 0; yy < ny; ++yy) {
            float* p0 = O0 + (size_t)(y0 + yy) * WD + x0;
            float* p1 = O1 + (size_t)(y0 + yy) * WD + x0;
            if (right) {    // cols 508,509,510 = s ; col 511 = 0
                *reinterpret_cast<float4*>(p0) = make_float4(s0, s0, s0, 0.f);
                *reinterpret_cast<float4*>(p1) = make_float4(s1, s1, s1, 0.f);
            } else {
                *reinterpret_cast<float2*>(p0) = make_float2(s0, s0);
                *reinterpret_cast<float2*>(p1) = make_float2(s1, s1);
            }
        }
        if (bottom) {       // row 511 = 0
            float* p0 = O0 + (size_t)(HD - 1) * WD + x0;
            float* p1 = O1 + (size_t)(HD - 1) * WD + x0;
            if (right) {
                *reinterpret_cast<float4*>(p0) = make_float4(0.f, 0.f, 0.f, 0.f);
                *reinterpret_cast<float4*>(p1) = make_float4(0.f, 0.f, 0.f, 0.f);
            } else {
                *reinterpret_cast<float2*>(p0) = make_float2(0.f, 0.f);
                *reinterpret_cast<float2*>(p1) = make_float2(0.f, 0.f);
            }
        }
    }
}

extern "C" void kernel_launch(void* const* d_in, const int* in_sizes, int n_in,
                              void* d_out, int out_size, void* d_ws, size_t ws_size,
                              hipStream_t stream) {
    const float* anchor = (const float*)d_in[0];
    const float* pos    = (const float*)d_in[1];
    const float* neg    = (const float*)d_in[2];
    float* out0 = (float*)d_out;
    float* out1 = out0 + (size_t)BATCH * HD * WD;

    dc_pool_kernel<<<NWG, NTHR, 0, stream>>>(anchor, pos, neg, out0, out1);
}